// Round 6
// baseline (388.393 us; speedup 1.0000x reference)
//
#include <hip/hip_runtime.h>
#include <math.h>

constexpr int Bn = 8, Ln = 2048, Dn = 512;
constexpr int Mn = Bn * Ln;  // 16384
constexpr int CONV_BLOCKS = Mn * Dn / 16 / 256;     // 2048 (4 l x 4 ch per thread)
constexpr int WPREP_BLOCKS = 448;                   // 7 x 64
constexpr int ZERO_FLOATS = 3 * Mn + 2 * Ln;        // Rv + MeanAcc + SS + RS
constexpr int ZERO_BLOCKS = ZERO_FLOATS / (256 * 4);  // 52

typedef __bf16 bf16x8 __attribute__((ext_vector_type(8)));
typedef __bf16 bf16x4v __attribute__((ext_vector_type(4)));
typedef float f32x4 __attribute__((ext_vector_type(4)));

__device__ __forceinline__ float gelu_exact(float x) {
    return 0.5f * x * (1.0f + erff(x * 0.7071067811865475f));
}
__device__ __forceinline__ float sigmoid_fast(float x) {
    return __builtin_amdgcn_rcpf(1.0f + __expf(-x));
}

// ---------------------------------------------------------------------------
// Fused prep: conv (blocks [0,CONV)), weight prep, zero atomic targets.
// Wall = [eta_w1^T ; alpha_w1^T ; q_w] (1536 x 512) bf16.
// ---------------------------------------------------------------------------
__global__ __launch_bounds__(256) void prep_kernel(
    const float* __restrict__ x, const float* __restrict__ w,
    const float* __restrict__ bias, __bf16* __restrict__ xcb,
    const float* __restrict__ ew1, const float* __restrict__ aw1,
    const float* __restrict__ ew2, const float* __restrict__ aw2,
    const float* __restrict__ mw1, const float* __restrict__ mw2,
    const float* __restrict__ qw,
    __bf16* __restrict__ Wall, __bf16* __restrict__ W2t,
    __bf16* __restrict__ m1t, __bf16* __restrict__ m2t,
    float* __restrict__ zero_zone) {
    __shared__ float tile[64][65];
    if (blockIdx.x < CONV_BLOCKS) {
        int idx = blockIdx.x * 256 + threadIdx.x;
        int g = idx & 127;
        int r4 = idx >> 7;
        int bl0 = r4 * 4;
        int l0 = bl0 & (Ln - 1);
        int d = g * 4;
        float4 b4 = *(const float4*)&bias[d];
        float wv[16];
        *(float4*)&wv[0]  = *(const float4*)&w[d * 4];
        *(float4*)&wv[4]  = *(const float4*)&w[d * 4 + 4];
        *(float4*)&wv[8]  = *(const float4*)&w[d * 4 + 8];
        *(float4*)&wv[12] = *(const float4*)&w[d * 4 + 12];
        float4 xv[7];
#pragma unroll
        for (int t = 0; t < 7; ++t) {
            int ll = l0 - 3 + t;
            xv[t] = (ll >= 0) ? *(const float4*)&x[(size_t)(bl0 - 3 + t) * Dn + d]
                              : make_float4(0.f, 0.f, 0.f, 0.f);
        }
#pragma unroll
        for (int i = 0; i < 4; ++i) {
            float a0 = b4.x, a1 = b4.y, a2 = b4.z, a3 = b4.w;
#pragma unroll
            for (int k = 0; k < 4; ++k) {
                float4 xt = xv[i + k];
                a0 += xt.x * wv[0 * 4 + k];
                a1 += xt.y * wv[1 * 4 + k];
                a2 += xt.z * wv[2 * 4 + k];
                a3 += xt.w * wv[3 * 4 + k];
            }
            bf16x4v o = { (__bf16)a0, (__bf16)a1, (__bf16)a2, (__bf16)a3 };
            *(bf16x4v*)&xcb[(size_t)(bl0 + i) * Dn + d] = o;
        }
        return;
    }
    if (blockIdx.x >= CONV_BLOCKS + WPREP_BLOCKS) {
        int idx = (blockIdx.x - CONV_BLOCKS - WPREP_BLOCKS) * 256 + threadIdx.x;
        ((float4*)zero_zone)[idx] = make_float4(0.f, 0.f, 0.f, 0.f);
        return;
    }
    int bid = blockIdx.x - CONV_BLOCKS;
    int z = bid >> 6;
    int t = bid & 63;
    int r0 = (t >> 3) * 64, c0 = (t & 7) * 64;
    const float* src;
    __bf16* dst;
    int trans = 1;
    switch (z) {
        case 0: src = ew1; dst = Wall; break;
        case 1: src = aw1; dst = Wall + 512 * 512; break;
        case 2: src = ew2; dst = W2t; break;
        case 3: src = aw2; dst = W2t + 512 * 512; break;
        case 4: src = mw1; dst = m1t; break;
        case 5: src = mw2; dst = m2t; break;
        default: src = qw; dst = Wall + 1024 * 512; trans = 0; break;
    }
    if (!trans) {
        for (int i = threadIdx.x; i < 4096; i += 256) {
            int r = i >> 6, c = i & 63;
            dst[(size_t)(r0 + r) * 512 + c0 + c] = (__bf16)src[(size_t)(r0 + r) * 512 + c0 + c];
        }
        return;
    }
    for (int i = threadIdx.x; i < 4096; i += 256) {
        int r = i >> 6, c = i & 63;
        tile[r][c] = src[(size_t)(r0 + r) * 512 + c0 + c];
    }
    __syncthreads();
    for (int i = threadIdx.x; i < 4096; i += 256) {
        int r = i >> 6, c = i & 63;
        dst[(size_t)(c0 + r) * 512 + r0 + c] = (__bf16)tile[c][r];
    }
}

// ---------------------------------------------------------------------------
// Register-fragment bf16 MFMA GEMM — NO LDS, NO barriers.
// Block = 128x128 (2x2 waves of 64x64). Fragments loaded straight from
// global (L2-resident B, L2/LLC-hot A), double-buffered in registers.
// OP 0: fused H|q.  x-blocks [0,8): H = gelu(acc) -> bf16 (ldc 1024)
//                   x-blocks [8,12): qraw -> bf16 + atomic SS/RS per row
// OP 1: sigmoid-mean: atomic per-l mean into red0[z*Ln + l]; no store
// OP 3: G = gelu(inv*(P*acc + Q*RS)) -> bf16 + atomic rowsum red0[row]
// OP 4: out = aux*inv + P*acc + Q*Rv  -> fp32
// ---------------------------------------------------------------------------
template <int OP>
__global__ __launch_bounds__(256, 3) void gemm_reg(
    const __bf16* __restrict__ A, int lda, int Az,
    const __bf16* __restrict__ Bt, int Bz,
    void* __restrict__ C0, void* __restrict__ C1,
    const __bf16* __restrict__ auxb,
    const float* __restrict__ Pv, const float* __restrict__ Qv,
    const float* __restrict__ SSv, const float* __restrict__ RSv,
    float* __restrict__ red0, float* __restrict__ red1, float* __restrict__ red2) {
    const int tid = threadIdx.x;
    const int lane = tid & 63, wv = tid >> 6;
    const int wm = wv & 1, wn = wv >> 1;
    const int fr = lane & 15, fq = lane >> 4;
    const int z = blockIdx.z;
    A += (size_t)z * Az;
    Bt += (size_t)z * Bz;
    const int row0 = blockIdx.y * 128 + wm * 64;
    const int col0 = blockIdx.x * 128 + wn * 64;
    const __bf16* Ap = A + (size_t)(row0 + fr) * lda + fq * 8;
    const __bf16* Bp = Bt + (size_t)(col0 + fr) * 512 + fq * 8;
    float* redp = (OP == 1) ? red0 + (size_t)z * Ln : red0;

    f32x4 acc[4][4] = {};
    bf16x8 ab[2][4], bb[2][4];
#pragma unroll
    for (int s = 0; s < 4; ++s) {
        ab[0][s] = *(const bf16x8*)(Ap + (size_t)s * 16 * lda);
        bb[0][s] = *(const bf16x8*)(Bp + s * 16 * 512);
    }
#pragma unroll
    for (int k0 = 0; k0 < 512; k0 += 32) {
        const int cur = (k0 >> 5) & 1, nxt = cur ^ 1;
        if (k0 < 480) {
#pragma unroll
            for (int s = 0; s < 4; ++s) {
                ab[nxt][s] = *(const bf16x8*)(Ap + (size_t)s * 16 * lda + k0 + 32);
                bb[nxt][s] = *(const bf16x8*)(Bp + s * 16 * 512 + k0 + 32);
            }
        }
#pragma unroll
        for (int mi = 0; mi < 4; ++mi)
#pragma unroll
            for (int ni = 0; ni < 4; ++ni)
                acc[mi][ni] = __builtin_amdgcn_mfma_f32_16x16x32_bf16(
                    ab[cur][mi], bb[cur][ni], acc[mi][ni], 0, 0, 0);
    }

    const bool qpath = (OP == 0) && (blockIdx.x >= 8);
#pragma unroll
    for (int mi = 0; mi < 4; ++mi) {
#pragma unroll
        for (int r = 0; r < 4; ++r) {
            int row = row0 + mi * 16 + fq * 4 + r;
            float p = 0.f, qs = 0.f, rs = 0.f, inv = 1.f;
            if (OP >= 3) {
                int t = row & (Ln - 1);
                p = Pv[t]; qs = Qv[t];
                rs = RSv[row];
                inv = 1.0f / fmaxf(sqrtf(SSv[row]), 1e-12f);
            }
            float s1 = 0.f, s2 = 0.f;
#pragma unroll
            for (int ni = 0; ni < 4; ++ni) {
                int col = col0 + ni * 16 + fr;
                float v = acc[mi][ni][r];
                if (OP == 0) {
                    if (!qpath) {
                        v = gelu_exact(v);
                        ((__bf16*)C0)[(size_t)row * 1024 + col] = (__bf16)v;
                    } else {
                        ((__bf16*)C1)[(size_t)row * 512 + col - 1024] = (__bf16)v;
                        s1 += v; s2 += v * v;
                    }
                } else if (OP == 1) {
                    v = sigmoid_fast((float)auxb[(size_t)row * 512 + col] + v);
                    s1 += v;
                } else if (OP == 3) {
                    v = gelu_exact(inv * (p * v + qs * rs));
                    ((__bf16*)C0)[(size_t)row * 512 + col] = (__bf16)v;
                    s1 += v;
                } else if (OP == 4) {
                    float qn = (float)auxb[(size_t)row * 512 + col] * inv;
                    ((float*)C0)[(size_t)row * 512 + col] = qn + p * v + qs * rs;
                }
            }
            if (OP == 1 || OP == 3 || (OP == 0 && qpath)) {
                s1 += __shfl_xor(s1, 1, 64);
                s1 += __shfl_xor(s1, 2, 64);
                s1 += __shfl_xor(s1, 4, 64);
                s1 += __shfl_xor(s1, 8, 64);
                if (OP == 0) {
                    s2 += __shfl_xor(s2, 1, 64);
                    s2 += __shfl_xor(s2, 2, 64);
                    s2 += __shfl_xor(s2, 4, 64);
                    s2 += __shfl_xor(s2, 8, 64);
                }
                if (fr == 0) {
                    if (OP == 1) atomicAdd(&redp[row & (Ln - 1)], s1 * (1.0f / 4096.0f));
                    else if (OP == 3) atomicAdd(&red0[row], s1);
                    else { atomicAdd(&red1[row], s2); atomicAdd(&red2[row], s1); }
                }
            }
        }
    }
}

// ---------------------------------------------------------------------------
// Parallel scan over L=2048 affine maps q -> a*q - 0.01*e.  Exclusive prefixes.
// ---------------------------------------------------------------------------
__global__ __launch_bounds__(256) void scan_kernel(const float* __restrict__ a,
                                                   const float* __restrict__ e,
                                                   float* __restrict__ P,
                                                   float* __restrict__ Q) {
    int tid = threadIdx.x;
    int base = tid * 8;
    float la[8], le[8], Aloc[8], Bloc[8];
#pragma unroll
    for (int j = 0; j < 8; ++j) { la[j] = a[base + j]; le[j] = e[base + j]; }
    float Ac = 1.f, Bc = 0.f;
#pragma unroll
    for (int j = 0; j < 8; ++j) {
        Aloc[j] = Ac; Bloc[j] = Bc;
        Bc = Bc * la[j] - 0.01f * le[j];
        Ac *= la[j];
    }
    float Aw = Ac, Bw = Bc;
#pragma unroll
    for (int off = 1; off < 64; off <<= 1) {
        float Ap = __shfl_up(Aw, off, 64);
        float Bp = __shfl_up(Bw, off, 64);
        if ((tid & 63) >= off) { Bw = Aw * Bp + Bw; Aw = Aw * Ap; }
    }
    __shared__ float wA[4], wB[4];
    if ((tid & 63) == 63) { wA[tid >> 6] = Aw; wB[tid >> 6] = Bw; }
    __syncthreads();
    float Apre = 1.f, Bpre = 0.f;
    for (int w = 0; w < (tid >> 6); ++w) { Bpre = wA[w] * Bpre + wB[w]; Apre = wA[w] * Apre; }
    float Ax = __shfl_up(Aw, 1, 64), Bx = __shfl_up(Bw, 1, 64);
    if ((tid & 63) == 0) { Ax = 1.f; Bx = 0.f; }
    float At = Ax * Apre, Bt2 = Ax * Bpre + Bx;
#pragma unroll
    for (int j = 0; j < 8; ++j) {
        P[base + j] = Aloc[j] * At;
        Q[base + j] = Aloc[j] * Bt2 + Bloc[j];
    }
}

// ---------------------------------------------------------------------------
extern "C" void kernel_launch(void* const* d_in, const int* in_sizes, int n_in,
                              void* d_out, int out_size, void* d_ws, size_t ws_size,
                              hipStream_t stream) {
    const float* x        = (const float*)d_in[0];
    const float* conv_w   = (const float*)d_in[1];
    const float* conv_b   = (const float*)d_in[2];
    const float* q_w      = (const float*)d_in[3];
    const float* mem_w1   = (const float*)d_in[4];
    const float* mem_w2   = (const float*)d_in[5];
    const float* eta_w1   = (const float*)d_in[6];
    const float* eta_w2   = (const float*)d_in[7];
    const float* alpha_w1 = (const float*)d_in[8];
    const float* alpha_w2 = (const float*)d_in[9];
    float* out = (float*)d_out;

    char* w = (char*)d_ws;
    __bf16* xcb  = (__bf16*)w;    w += (size_t)Mn * Dn * 2;
    __bf16* H    = (__bf16*)w;    w += (size_t)Mn * 1024 * 2;
    __bf16* qb   = (__bf16*)w;    w += (size_t)Mn * Dn * 2;
    __bf16* G    = (__bf16*)w;    w += (size_t)Mn * Dn * 2;
    __bf16* Wall = (__bf16*)w;    w += (size_t)1536 * 512 * 2;
    __bf16* W2t  = (__bf16*)w;    w += (size_t)2 * 512 * 512 * 2;
    __bf16* m1t  = (__bf16*)w;    w += (size_t)512 * 512 * 2;
    __bf16* m2t  = (__bf16*)w;    w += (size_t)512 * 512 * 2;
    float* Rv      = (float*)w;   w += (size_t)Mn * 4;            // zero zone start
    float* MeanAcc = (float*)w;   w += (size_t)2 * Ln * 4;
    float* SS      = (float*)w;   w += (size_t)Mn * 4;
    float* RS      = (float*)w;   w += (size_t)Mn * 4;            // zero zone end
    float* Pv = (float*)w;        w += Ln * 4;
    float* Qv = (float*)w;        w += Ln * 4;

    // 1. conv + weight prep + zero (fused)
    prep_kernel<<<CONV_BLOCKS + WPREP_BLOCKS + ZERO_BLOCKS, 256, 0, stream>>>(
        x, conv_w, conv_b, xcb, eta_w1, alpha_w1, eta_w2, alpha_w2,
        mem_w1, mem_w2, q_w, Wall, W2t, m1t, m2t, Rv);
    // 2. fused: H = gelu(xcb @ [ew1|aw1]) ; qraw = xcb @ qw^T (+SS/RS atomics)
    gemm_reg<0><<<dim3(12, 128), 256, 0, stream>>>(
        xcb, 512, 0, Wall, 0, H, qb, nullptr,
        nullptr, nullptr, nullptr, nullptr, nullptr, SS, RS);
    // 3. per-l means of sigmoid(xc + H_half @ w2)  (z=0 eta, z=1 alpha)
    gemm_reg<1><<<dim3(4, 128, 2), 256, 0, stream>>>(
        H, 1024, 512, W2t, 512 * 512, nullptr, nullptr, xcb,
        nullptr, nullptr, nullptr, nullptr, MeanAcc, nullptr, nullptr);
    // 4. P/Q prefix scan (a = alpha, e = eta)
    scan_kernel<<<1, 256, 0, stream>>>(MeanAcc + Ln, MeanAcc, Pv, Qv);
    // 5. G = gelu(inv*(P*(qraw@m1) + Q*RS)) + fused rowsum Rv
    gemm_reg<3><<<dim3(4, 128), 256, 0, stream>>>(
        qb, 512, 0, m1t, 0, G, nullptr, nullptr,
        Pv, Qv, SS, RS, Rv, nullptr, nullptr);
    // 6. out = qraw*inv + P*(G@m2) + Q*Rv
    gemm_reg<4><<<dim3(4, 128), 256, 0, stream>>>(
        G, 512, 0, m2t, 0, out, nullptr, qb,
        Pv, Qv, SS, Rv, nullptr, nullptr, nullptr);
}

// Round 7
// 227.507 us; speedup vs baseline: 1.7072x; 1.7072x over previous
//
#include <hip/hip_runtime.h>
#include <math.h>

constexpr int Bn = 8, Ln = 2048, Dn = 512;
constexpr int Mn = Bn * Ln;  // 16384
constexpr int CONV_BLOCKS = Mn * Dn / 16 / 256;     // 2048 (4 l x 4 ch per thread)
constexpr int WPREP_BLOCKS = 448;                   // 7 x 64
constexpr int ZERO_FLOATS = 3 * Mn + 2 * Ln;        // Rv + MeanAcc + SS + RS
constexpr int ZERO_BLOCKS = ZERO_FLOATS / (256 * 4);  // 52

typedef __bf16 bf16x8 __attribute__((ext_vector_type(8)));
typedef __bf16 bf16x4v __attribute__((ext_vector_type(4)));
typedef float f32x4 __attribute__((ext_vector_type(4)));

__device__ __forceinline__ float sigmoid_fast(float x) {
    return __builtin_amdgcn_rcpf(1.0f + __expf(-x));
}
// tanh-form gelu: x*sigmoid(2*0.7978845608*(x+0.044715 x^3)); max err ~7.5e-4
__device__ __forceinline__ float gelu_fast(float x) {
    return x * sigmoid_fast(1.5957691216f * (x + 0.044715f * x * x * x));
}

// ---------------------------------------------------------------------------
// Fused prep: conv (blocks [0,CONV)), weight prep, zero atomic targets.
// Wall = [eta_w1^T ; alpha_w1^T ; q_w] (1536 x 512) bf16.
// ---------------------------------------------------------------------------
__global__ __launch_bounds__(256) void prep_kernel(
    const float* __restrict__ x, const float* __restrict__ w,
    const float* __restrict__ bias, __bf16* __restrict__ xcb,
    const float* __restrict__ ew1, const float* __restrict__ aw1,
    const float* __restrict__ ew2, const float* __restrict__ aw2,
    const float* __restrict__ mw1, const float* __restrict__ mw2,
    const float* __restrict__ qw,
    __bf16* __restrict__ Wall, __bf16* __restrict__ W2t,
    __bf16* __restrict__ m1t, __bf16* __restrict__ m2t,
    float* __restrict__ zero_zone) {
    __shared__ float tile[64][65];
    if (blockIdx.x < CONV_BLOCKS) {
        int idx = blockIdx.x * 256 + threadIdx.x;
        int g = idx & 127;
        int r4 = idx >> 7;
        int bl0 = r4 * 4;
        int l0 = bl0 & (Ln - 1);
        int d = g * 4;
        float4 b4 = *(const float4*)&bias[d];
        float wv[16];
        *(float4*)&wv[0]  = *(const float4*)&w[d * 4];
        *(float4*)&wv[4]  = *(const float4*)&w[d * 4 + 4];
        *(float4*)&wv[8]  = *(const float4*)&w[d * 4 + 8];
        *(float4*)&wv[12] = *(const float4*)&w[d * 4 + 12];
        float4 xv[7];
#pragma unroll
        for (int t = 0; t < 7; ++t) {
            int ll = l0 - 3 + t;
            xv[t] = (ll >= 0) ? *(const float4*)&x[(size_t)(bl0 - 3 + t) * Dn + d]
                              : make_float4(0.f, 0.f, 0.f, 0.f);
        }
#pragma unroll
        for (int i = 0; i < 4; ++i) {
            float a0 = b4.x, a1 = b4.y, a2 = b4.z, a3 = b4.w;
#pragma unroll
            for (int k = 0; k < 4; ++k) {
                float4 xt = xv[i + k];
                a0 += xt.x * wv[0 * 4 + k];
                a1 += xt.y * wv[1 * 4 + k];
                a2 += xt.z * wv[2 * 4 + k];
                a3 += xt.w * wv[3 * 4 + k];
            }
            bf16x4v o = { (__bf16)a0, (__bf16)a1, (__bf16)a2, (__bf16)a3 };
            *(bf16x4v*)&xcb[(size_t)(bl0 + i) * Dn + d] = o;
        }
        return;
    }
    if (blockIdx.x >= CONV_BLOCKS + WPREP_BLOCKS) {
        int idx = (blockIdx.x - CONV_BLOCKS - WPREP_BLOCKS) * 256 + threadIdx.x;
        ((float4*)zero_zone)[idx] = make_float4(0.f, 0.f, 0.f, 0.f);
        return;
    }
    int bid = blockIdx.x - CONV_BLOCKS;
    int z = bid >> 6;
    int t = bid & 63;
    int r0 = (t >> 3) * 64, c0 = (t & 7) * 64;
    const float* src;
    __bf16* dst;
    int trans = 1;
    switch (z) {
        case 0: src = ew1; dst = Wall; break;
        case 1: src = aw1; dst = Wall + 512 * 512; break;
        case 2: src = ew2; dst = W2t; break;
        case 3: src = aw2; dst = W2t + 512 * 512; break;
        case 4: src = mw1; dst = m1t; break;
        case 5: src = mw2; dst = m2t; break;
        default: src = qw; dst = Wall + 1024 * 512; trans = 0; break;
    }
    if (!trans) {
        for (int i = threadIdx.x; i < 4096; i += 256) {
            int r = i >> 6, c = i & 63;
            dst[(size_t)(r0 + r) * 512 + c0 + c] = (__bf16)src[(size_t)(r0 + r) * 512 + c0 + c];
        }
        return;
    }
    for (int i = threadIdx.x; i < 4096; i += 256) {
        int r = i >> 6, c = i & 63;
        tile[r][c] = src[(size_t)(r0 + r) * 512 + c0 + c];
    }
    __syncthreads();
    for (int i = threadIdx.x; i < 4096; i += 256) {
        int r = i >> 6, c = i & 63;
        dst[(size_t)(c0 + r) * 512 + r0 + c] = (__bf16)tile[c][r];
    }
}

// ---------------------------------------------------------------------------
// bf16 MFMA GEMM, BM x 128 tile, K = 512, BK = 64 (two 32-k sub-tiles per
// barrier: LDS = [rows x 32k | rows x 32k], preserving the wave-uniform
// global_load_lds layout and 64B row stride).  8 barriers instead of 16.
// OP 0: fused H|q.  x-blocks [0,8): H = gelu(acc) -> bf16 (ldc 1024)
//                   x-blocks [8,12): qraw -> bf16 + atomic SS/RS per row
// OP 1: sigmoid-mean: atomic per-l mean into red0[z*Ln + l]; no store
// OP 3: G = gelu(inv*(P*acc + Q*RS)) -> bf16 + atomic rowsum red0[row]
// OP 4: out = aux*inv + P*acc + Q*Rv  -> fp32
// ---------------------------------------------------------------------------
template <int OP, int BM>
__global__ __launch_bounds__(256, 4) void gemm_mfma(
    const __bf16* __restrict__ A, int lda, int Az,
    const __bf16* __restrict__ Bt, int Bz,
    void* __restrict__ C0, void* __restrict__ C1,
    const __bf16* __restrict__ auxb,
    const float* __restrict__ Pv, const float* __restrict__ Qv,
    const float* __restrict__ SSv, const float* __restrict__ RSv,
    float* __restrict__ red0, float* __restrict__ red1, float* __restrict__ red2) {
    constexpr int MI = BM / 32;          // 16-row frags per wave
    constexpr int AISS = BM / 32;        // A staging issues (BK=64): BM*64*2/256/16
    constexpr int ACH = BM * 4;          // A chunks (8 elems) per 32-k half
    __shared__ __align__(16) __bf16 Asl[BM * 64];
    __shared__ __align__(16) __bf16 Bsl[128 * 64];
    const int tid = threadIdx.x;
    const int lane = tid & 63, wv = tid >> 6;
    const int wm = wv & 1, wn = wv >> 1;
    const int fr = lane & 15, fq = lane >> 4;
    const int z = blockIdx.z;
    A += (size_t)z * Az;
    Bt += (size_t)z * Bz;
    const __bf16* Ab = A + (size_t)blockIdx.y * BM * lda;
    const __bf16* Bb = Bt + (size_t)blockIdx.x * 128 * 512;
    float* redp = (OP == 1) ? red0 + (size_t)z * Ln : red0;

    f32x4 acc[MI][4] = {};

    for (int k0 = 0; k0 < 512; k0 += 64) {
#pragma unroll
        for (int i = 0; i < AISS; ++i) {
            int c = tid + i * 256;
            int s = c / ACH;                 // which 32-k half
            int cl = c - s * ACH;
            int r = cl >> 2, co = (cl & 3) * 8 + s * 32;
            __builtin_amdgcn_global_load_lds(
                (const __attribute__((address_space(1))) void*)(Ab + (size_t)r * lda + k0 + co),
                (__attribute__((address_space(3))) void*)(Asl + c * 8), 16, 0, 0);
        }
#pragma unroll
        for (int i = 0; i < 4; ++i) {
            int c = tid + i * 256;
            int s = c >> 9;
            int cl = c & 511;
            int r = cl >> 2, co = (cl & 3) * 8 + s * 32;
            __builtin_amdgcn_global_load_lds(
                (const __attribute__((address_space(1))) void*)(Bb + (size_t)r * 512 + k0 + co),
                (__attribute__((address_space(3))) void*)(Bsl + c * 8), 16, 0, 0);
        }
        __syncthreads();
#pragma unroll
        for (int ks = 0; ks < 2; ++ks) {
            bf16x8 af[MI], bfr[4];
#pragma unroll
            for (int mi = 0; mi < MI; ++mi)
                af[mi] = *(const bf16x8*)&Asl[ks * BM * 32 +
                                              (wm * (BM / 2) + mi * 16 + fr) * 32 + fq * 8];
#pragma unroll
            for (int ni = 0; ni < 4; ++ni)
                bfr[ni] = *(const bf16x8*)&Bsl[ks * 4096 +
                                               (wn * 64 + ni * 16 + fr) * 32 + fq * 8];
#pragma unroll
            for (int mi = 0; mi < MI; ++mi)
#pragma unroll
                for (int ni = 0; ni < 4; ++ni)
                    acc[mi][ni] = __builtin_amdgcn_mfma_f32_16x16x32_bf16(
                        af[mi], bfr[ni], acc[mi][ni], 0, 0, 0);
        }
        __syncthreads();
    }

    const int row_base = blockIdx.y * BM + wm * (BM / 2);
    const int col_base = blockIdx.x * 128 + wn * 64;
    const bool qpath = (OP == 0) && (blockIdx.x >= 8);
#pragma unroll
    for (int mi = 0; mi < MI; ++mi) {
#pragma unroll
        for (int r = 0; r < 4; ++r) {
            int row = row_base + mi * 16 + fq * 4 + r;
            float p = 0.f, qs = 0.f, rs = 0.f, inv = 1.f;
            if (OP >= 3) {
                int t = row & (Ln - 1);
                p = Pv[t]; qs = Qv[t];
                rs = RSv[row];
                inv = 1.0f / fmaxf(sqrtf(SSv[row]), 1e-12f);
            }
            float s1 = 0.f, s2 = 0.f;
#pragma unroll
            for (int ni = 0; ni < 4; ++ni) {
                int col = col_base + ni * 16 + fr;
                float v = acc[mi][ni][r];
                if (OP == 0) {
                    if (!qpath) {
                        v = gelu_fast(v);
                        ((__bf16*)C0)[(size_t)row * 1024 + col] = (__bf16)v;
                    } else {
                        ((__bf16*)C1)[(size_t)row * 512 + col - 1024] = (__bf16)v;
                        s1 += v; s2 += v * v;
                    }
                } else if (OP == 1) {
                    v = sigmoid_fast((float)auxb[(size_t)row * 512 + col] + v);
                    s1 += v;
                } else if (OP == 3) {
                    v = gelu_fast(inv * (p * v + qs * rs));
                    ((__bf16*)C0)[(size_t)row * 512 + col] = (__bf16)v;
                    s1 += v;
                } else if (OP == 4) {
                    float qn = (float)auxb[(size_t)row * 512 + col] * inv;
                    ((float*)C0)[(size_t)row * 512 + col] = qn + p * v + qs * rs;
                }
            }
            if (OP == 1 || OP == 3 || (OP == 0 && qpath)) {
                s1 += __shfl_xor(s1, 1, 64);
                s1 += __shfl_xor(s1, 2, 64);
                s1 += __shfl_xor(s1, 4, 64);
                s1 += __shfl_xor(s1, 8, 64);
                if (OP == 0) {
                    s2 += __shfl_xor(s2, 1, 64);
                    s2 += __shfl_xor(s2, 2, 64);
                    s2 += __shfl_xor(s2, 4, 64);
                    s2 += __shfl_xor(s2, 8, 64);
                }
                if (fr == 0) {
                    if (OP == 1) atomicAdd(&redp[row & (Ln - 1)], s1 * (1.0f / 4096.0f));
                    else if (OP == 3) atomicAdd(&red0[row], s1);
                    else { atomicAdd(&red1[row], s2); atomicAdd(&red2[row], s1); }
                }
            }
        }
    }
}

// ---------------------------------------------------------------------------
// Parallel scan over L=2048 affine maps q -> a*q - 0.01*e.  Exclusive prefixes.
// ---------------------------------------------------------------------------
__global__ __launch_bounds__(256) void scan_kernel(const float* __restrict__ a,
                                                   const float* __restrict__ e,
                                                   float* __restrict__ P,
                                                   float* __restrict__ Q) {
    int tid = threadIdx.x;
    int base = tid * 8;
    float la[8], le[8], Aloc[8], Bloc[8];
#pragma unroll
    for (int j = 0; j < 8; ++j) { la[j] = a[base + j]; le[j] = e[base + j]; }
    float Ac = 1.f, Bc = 0.f;
#pragma unroll
    for (int j = 0; j < 8; ++j) {
        Aloc[j] = Ac; Bloc[j] = Bc;
        Bc = Bc * la[j] - 0.01f * le[j];
        Ac *= la[j];
    }
    float Aw = Ac, Bw = Bc;
#pragma unroll
    for (int off = 1; off < 64; off <<= 1) {
        float Ap = __shfl_up(Aw, off, 64);
        float Bp = __shfl_up(Bw, off, 64);
        if ((tid & 63) >= off) { Bw = Aw * Bp + Bw; Aw = Aw * Ap; }
    }
    __shared__ float wA[4], wB[4];
    if ((tid & 63) == 63) { wA[tid >> 6] = Aw; wB[tid >> 6] = Bw; }
    __syncthreads();
    float Apre = 1.f, Bpre = 0.f;
    for (int w = 0; w < (tid >> 6); ++w) { Bpre = wA[w] * Bpre + wB[w]; Apre = wA[w] * Apre; }
    float Ax = __shfl_up(Aw, 1, 64), Bx = __shfl_up(Bw, 1, 64);
    if ((tid & 63) == 0) { Ax = 1.f; Bx = 0.f; }
    float At = Ax * Apre, Bt2 = Ax * Bpre + Bx;
#pragma unroll
    for (int j = 0; j < 8; ++j) {
        P[base + j] = Aloc[j] * At;
        Q[base + j] = Aloc[j] * Bt2 + Bloc[j];
    }
}

// ---------------------------------------------------------------------------
extern "C" void kernel_launch(void* const* d_in, const int* in_sizes, int n_in,
                              void* d_out, int out_size, void* d_ws, size_t ws_size,
                              hipStream_t stream) {
    const float* x        = (const float*)d_in[0];
    const float* conv_w   = (const float*)d_in[1];
    const float* conv_b   = (const float*)d_in[2];
    const float* q_w      = (const float*)d_in[3];
    const float* mem_w1   = (const float*)d_in[4];
    const float* mem_w2   = (const float*)d_in[5];
    const float* eta_w1   = (const float*)d_in[6];
    const float* eta_w2   = (const float*)d_in[7];
    const float* alpha_w1 = (const float*)d_in[8];
    const float* alpha_w2 = (const float*)d_in[9];
    float* out = (float*)d_out;

    char* w = (char*)d_ws;
    __bf16* xcb  = (__bf16*)w;    w += (size_t)Mn * Dn * 2;
    __bf16* H    = (__bf16*)w;    w += (size_t)Mn * 1024 * 2;
    __bf16* qb   = (__bf16*)w;    w += (size_t)Mn * Dn * 2;
    __bf16* G    = (__bf16*)w;    w += (size_t)Mn * Dn * 2;
    __bf16* Wall = (__bf16*)w;    w += (size_t)1536 * 512 * 2;
    __bf16* W2t  = (__bf16*)w;    w += (size_t)2 * 512 * 512 * 2;
    __bf16* m1t  = (__bf16*)w;    w += (size_t)512 * 512 * 2;
    __bf16* m2t  = (__bf16*)w;    w += (size_t)512 * 512 * 2;
    float* Rv      = (float*)w;   w += (size_t)Mn * 4;            // zero zone start
    float* MeanAcc = (float*)w;   w += (size_t)2 * Ln * 4;
    float* SS      = (float*)w;   w += (size_t)Mn * 4;
    float* RS      = (float*)w;   w += (size_t)Mn * 4;            // zero zone end
    float* Pv = (float*)w;        w += Ln * 4;
    float* Qv = (float*)w;        w += Ln * 4;

    // 1. conv + weight prep + zero (fused)
    prep_kernel<<<CONV_BLOCKS + WPREP_BLOCKS + ZERO_BLOCKS, 256, 0, stream>>>(
        x, conv_w, conv_b, xcb, eta_w1, alpha_w1, eta_w2, alpha_w2,
        mem_w1, mem_w2, q_w, Wall, W2t, m1t, m2t, Rv);
    // 2. fused: H = gelu(xcb @ [ew1|aw1]) ; qraw = xcb @ qw^T (+SS/RS atomics)
    gemm_mfma<0, 128><<<dim3(12, 128), 256, 0, stream>>>(
        xcb, 512, 0, Wall, 0, H, qb, nullptr,
        nullptr, nullptr, nullptr, nullptr, nullptr, SS, RS);
    // 3. per-l means of sigmoid(xc + H_half @ w2)  (z=0 eta, z=1 alpha)
    gemm_mfma<1, 128><<<dim3(4, 128, 2), 256, 0, stream>>>(
        H, 1024, 512, W2t, 512 * 512, nullptr, nullptr, xcb,
        nullptr, nullptr, nullptr, nullptr, MeanAcc, nullptr, nullptr);
    // 4. P/Q prefix scan (a = alpha, e = eta)
    scan_kernel<<<1, 256, 0, stream>>>(MeanAcc + Ln, MeanAcc, Pv, Qv);
    // 5. G = gelu(inv*(P*(qraw@m1) + Q*RS)) + fused rowsum Rv
    gemm_mfma<3, 64><<<dim3(4, 256), 256, 0, stream>>>(
        qb, 512, 0, m1t, 0, G, nullptr, nullptr,
        Pv, Qv, SS, RS, Rv, nullptr, nullptr);
    // 6. out = qraw*inv + P*(G@m2) + Q*Rv
    gemm_mfma<4, 64><<<dim3(4, 256), 256, 0, stream>>>(
        G, 512, 0, m2t, 0, out, nullptr, qb,
        Pv, Qv, SS, Rv, nullptr, nullptr, nullptr);
}